// Round 1
// baseline (678.334 us; speedup 1.0000x reference)
//
#include <hip/hip_runtime.h>
#include <math.h>

#define NT   256
#define N2   2048   // half-size complex FFT for real-packed forward
#define NF   4096   // full FFT size (= L)
#define FBINS 2049  // rfft bins 0..2048
#define KTOP 64
#define BB   32
#define LL   4096
#define CC   128

union SMem {
    struct {  // forward phase (fp64): 16+16+8+8 = 48 KB
        double zre[N2], zim[N2];
        double tc[N2/2], ts[N2/2];
    } f;
    struct {  // inverse phase (fp32): 16+16+8+8 = 48 KB
        float sre[NF], sim[NF];
        float itc[NF/2], its[NF/2];
    } inv;
};

__global__ __launch_bounds__(NT)
void fourier_topk_kernel(const float* __restrict__ x, float* __restrict__ out) {
    __shared__ SMem u;
    __shared__ float Xre[FBINS], Xim[FBINS], amp2[FBINS];
    __shared__ unsigned char keep[FBINS];
    __shared__ int red[NT/64];

    const int tid = threadIdx.x;

    // ---- block -> (b,c) swizzle: keep one 16-channel cache line's 16 blocks
    // on the same XCD (HW round-robins blockIdx % 8 across XCDs).
    int d = blockIdx.x;
    int xcd = d & 7, slot = d >> 3;           // slot 0..511
    int cid = xcd * 32 + (slot >> 4);         // 256 clusters of 16 channels
    int within = slot & 15;
    int b = cid >> 3;                          // 0..31
    int c = ((cid & 7) << 4) + within;         // 0..127

    const float* xp = x + (size_t)b * LL * CC + c;

    // ---- fp64 twiddle table W_2048^k = exp(-2*pi*i*k/2048), k<1024
    for (int k = tid; k < N2/2; k += NT) {
        double s, cc;
        sincospi(-(double)k / 1024.0, &s, &cc);
        u.f.tc[k] = cc; u.f.ts[k] = s;
    }
    // ---- load real series packed: z[m] = x[2m] + i*x[2m+1]
    for (int i = 0; i < N2/NT; ++i) {
        int m = tid + NT*i;
        u.f.zre[m] = (double)xp[(size_t)(2*m)   * CC];
        u.f.zim[m] = (double)xp[(size_t)(2*m+1) * CC];
    }
    __syncthreads();

    // ---- forward radix-2 DIF (fp64), natural -> bit-reversed
    int wstep = 1;
    for (int half = N2/2; half >= 1; half >>= 1) {
        for (int i = 0; i < (N2/2)/NT; ++i) {
            int bf = tid + NT*i;
            int j  = bf & (half-1);
            int a  = ((bf & ~(half-1)) << 1) | j;
            int bx = a + half;
            double ar = u.f.zre[a],  ai = u.f.zim[a];
            double br = u.f.zre[bx], bi = u.f.zim[bx];
            double sr = ar + br, si = ai + bi;
            double dr = ar - br, di = ai - bi;
            int twi = j * wstep;
            double wc = u.f.tc[twi], ws = u.f.ts[twi];
            u.f.zre[a]  = sr;             u.f.zim[a]  = si;
            u.f.zre[bx] = dr*wc - di*ws;  u.f.zim[bx] = dr*ws + di*wc;
        }
        wstep <<= 1;
        __syncthreads();
    }

    // ---- untwiddle to rfft bins X[0..2048]; amp^2 (fp64 -> fp32 keys)
    for (int k = tid; k <= N2; k += NT) {
        int k1 = k & (N2-1);
        int k2 = (N2 - k1) & (N2-1);
        int pa = __brev((unsigned)k1) >> 21;   // 11-bit reversal
        int pb = __brev((unsigned)k2) >> 21;
        double ar = u.f.zre[pa], ai = u.f.zim[pa];
        double br = u.f.zre[pb], bi = u.f.zim[pb];
        double Er = 0.5*(ar + br), Ei = 0.5*(ai - bi);
        double Or = 0.5*(ai + bi), Oi = 0.5*(br - ar);
        double s, cc;
        sincospi(-(double)k / 2048.0, &s, &cc);
        double Xr = Er + cc*Or - s*Oi;
        double Xi = Ei + cc*Oi + s*Or;
        Xre[k] = (float)Xr; Xim[k] = (float)Xi;
        amp2[k] = (float)(Xr*Xr + Xi*Xi);
    }
    __syncthreads();

    // ---- exact top-64 threshold: bitwise descent on fp32 bit patterns
    unsigned int av[9]; int nl = 0;
    for (int k = tid; k <= N2; k += NT) av[nl++] = __float_as_uint(amp2[k]);

    unsigned int prefix = 0;
    for (int bit = 30; bit >= 0; --bit) {
        unsigned int cand = prefix | (1u << bit);
        int cnt = 0;
        for (int q = 0; q < nl; ++q) cnt += (av[q] >= cand) ? 1 : 0;
        for (int off = 1; off < 64; off <<= 1) cnt += __shfl_xor(cnt, off);
        if ((tid & 63) == 0) red[tid >> 6] = cnt;
        __syncthreads();
        int tot = red[0] + red[1] + red[2] + red[3];
        if (tot >= KTOP) prefix = cand;
        __syncthreads();
    }
    // counts at threshold (packed reduce: ge | gt<<16)
    int cge = 0, cgt = 0;
    for (int q = 0; q < nl; ++q) {
        cge += (av[q] >= prefix) ? 1 : 0;
        cgt += (av[q] >  prefix) ? 1 : 0;
    }
    int packed = cge | (cgt << 16);
    for (int off = 1; off < 64; off <<= 1) packed += __shfl_xor(packed, off);
    if ((tid & 63) == 0) red[tid >> 6] = packed;
    __syncthreads();
    int tot = red[0] + red[1] + red[2] + red[3];
    cge = tot & 0xFFFF; cgt = tot >> 16;
    __syncthreads();

    if (cge == KTOP) {
        for (int k = tid; k <= N2; k += NT)
            keep[k] = (__float_as_uint(amp2[k]) >= prefix) ? 1 : 0;
    } else {
        for (int k = tid; k <= N2; k += NT) {
            unsigned int vb = __float_as_uint(amp2[k]);
            keep[k] = (vb > prefix) ? 1 : ((vb == prefix) ? 2 : 0);
        }
        __syncthreads();
        if (tid == 0) {  // rare tie path: keep lowest indices among equals
            int need_eq = KTOP - cgt, taken = 0;
            for (int k = 0; k <= N2; ++k)
                if (keep[k] == 2) { keep[k] = (taken < need_eq) ? 1 : 0; ++taken; }
        }
    }
    __syncthreads();

    // ---- zero spectrum buffer + fp32 inverse twiddles W_4096^-k (= e^{+2pi i k/4096})
    for (int i = 0; i < NF/NT; ++i) {
        int p = tid + NT*i;
        u.inv.sre[p] = 0.f; u.inv.sim[p] = 0.f;
    }
    for (int k = tid; k < NF/2; k += NT) {
        float s, cc;
        sincospif((float)k / 2048.f, &s, &cc);
        u.inv.itc[k] = cc; u.inv.its[k] = s;
    }
    __syncthreads();

    // ---- scatter kept bins (+ hermitian mirror) into bit-reversed positions
    for (int k = tid; k <= N2; k += NT) {
        if (keep[k]) {
            float xr = Xre[k], xi = Xim[k];
            int p = __brev((unsigned)k) >> 20;         // 12-bit reversal
            u.inv.sre[p] = xr; u.inv.sim[p] = xi;
            if (k != 0 && k != N2) {
                int q = __brev((unsigned)(NF - k)) >> 20;
                u.inv.sre[q] = xr; u.inv.sim[q] = -xi;
            }
        }
    }
    __syncthreads();

    // ---- inverse radix-2 DIT (fp32), bit-reversed -> natural
    int iws = N2;  // NF/(2*half) at half=1
    for (int half = 1; half < NF; half <<= 1) {
        for (int i = 0; i < (NF/2)/NT; ++i) {
            int bf = tid + NT*i;
            int j  = bf & (half-1);
            int a  = ((bf & ~(half-1)) << 1) | j;
            int bx = a + half;
            int twi = j * iws;
            float wc = u.inv.itc[twi], ws = u.inv.its[twi];
            float br = u.inv.sre[bx], bi = u.inv.sim[bx];
            float tr = br*wc - bi*ws;
            float ti = br*ws + bi*wc;
            float ar = u.inv.sre[a], ai = u.inv.sim[a];
            u.inv.sre[a]  = ar + tr; u.inv.sim[a]  = ai + ti;
            u.inv.sre[bx] = ar - tr; u.inv.sim[bx] = ai - ti;
        }
        iws >>= 1;
        __syncthreads();
    }

    // ---- write real part, 1/N normalization
    float* op = out + (size_t)b * LL * CC + c;
    const float invN = 1.0f / (float)NF;
    for (int i = 0; i < NF/NT; ++i) {
        int t = tid + NT*i;
        op[(size_t)t * CC] = u.inv.sre[t] * invN;
    }
}

extern "C" void kernel_launch(void* const* d_in, const int* in_sizes, int n_in,
                              void* d_out, int out_size, void* d_ws, size_t ws_size,
                              hipStream_t stream) {
    (void)in_sizes; (void)n_in; (void)d_ws; (void)ws_size; (void)out_size;
    const float* x = (const float*)d_in[0];
    float* out = (float*)d_out;
    dim3 grid(BB * CC), block(NT);
    hipLaunchKernelGGL(fourier_topk_kernel, grid, block, 0, stream, x, out);
}

// Round 2
// 378.405 us; speedup vs baseline: 1.7926x; 1.7926x over previous
//
#include <hip/hip_runtime.h>
#include <math.h>

#define NT   256
#define N2   2048   // half-size complex FFT for real-packed forward
#define NF   4096   // full length L
#define KTOP 64
#define BB   32
#define LL   4096
#define CC   128
#define PD(i) ((i) + ((i) >> 5))   // pad 1 per 32: power-of-2 strides -> <=2-way

__global__ void init_tables_kernel(double2* __restrict__ Wt, double2* __restrict__ Ut) {
    int i = blockIdx.x * 256 + threadIdx.x;
    if (i < 1024) {  // fwd twiddles W_2048^i = exp(-2*pi*i/2048)
        double s, c; sincospi(-(double)i / 1024.0, &s, &c);
        Wt[i] = make_double2(c, s);
    }
    if (i < 2049) {  // untwiddle exp(-i*pi*k/2048)
        double s, c; sincospi(-(double)i / 2048.0, &s, &c);
        Ut[i] = make_double2(c, s);
    }
}

template<bool USE_WS>
__global__ __launch_bounds__(NT, 4)
void fourier_topk_kernel(const float* __restrict__ x, float* __restrict__ out,
                         const double2* __restrict__ Wt, const double2* __restrict__ Ut) {
    __shared__ double zre[N2 + (N2 >> 5)], zim[N2 + (N2 >> 5)];  // 33.8 KB
    __shared__ int red[2][4];
    __shared__ int eqc[9][4];
    __shared__ float4 listf[KTOP];
    __shared__ int listk[KTOP];
    __shared__ int nlist;

    const int tid  = threadIdx.x;
    const int lane = tid & 63;
    const int w    = tid >> 6;

    // XCD-aware swizzle: 16 consecutive channels stay on one XCD (L2 line reuse)
    int d = blockIdx.x;
    int xcd = d & 7, slot = d >> 3;
    int cid = xcd * 32 + (slot >> 4);
    int within = slot & 15;
    int b = cid >> 3;
    int c = ((cid & 7) << 4) + within;

    const float* xp = x + (size_t)b * LL * CC + c;

    if (tid == 0) nlist = 0;
    // load real series packed: z[m] = x[2m] + i*x[2m+1]
    #pragma unroll
    for (int i = 0; i < N2 / NT; ++i) {
        int m = tid + NT * i;
        zre[PD(m)] = (double)xp[(size_t)(2 * m)     * CC];
        zim[PD(m)] = (double)xp[(size_t)(2 * m + 1) * CC];
    }
    __syncthreads();

    // ---- forward radix-2 DIF (fp64), natural -> bit-reversed
    int wstep = 1;
    for (int half = N2 / 2; half >= 1; half >>= 1) {
        #pragma unroll
        for (int i = 0; i < (N2 / 2) / NT; ++i) {
            int bf = tid + NT * i;
            int j  = bf & (half - 1);
            int a  = ((bf & ~(half - 1)) << 1) | j;
            int bx = a + half;
            int pa = PD(a), pb = PD(bx);
            double ar = zre[pa], ai = zim[pa];
            double br = zre[pb], bi = zim[pb];
            double sr = ar + br, si = ai + bi;
            double dr = ar - br, di = ai - bi;
            int twi = j * wstep;
            double wc, wsn;
            if (USE_WS) { double2 wv = Wt[twi]; wc = wv.x; wsn = wv.y; }
            else        { sincospi(-(double)twi / 1024.0, &wsn, &wc); }
            zre[pa] = sr;               zim[pa] = si;
            zre[pb] = dr * wc - di * wsn;
            zim[pb] = dr * wsn + di * wc;
        }
        wstep <<= 1;
        __syncthreads();
    }

    // ---- untwiddle to rfft bins; X and keys stay in REGISTERS
    unsigned ku[9]; float fxr[9], fxi[9];
    #pragma unroll
    for (int q = 0; q < 9; ++q) {
        ku[q] = 0u; fxr[q] = 0.f; fxi[q] = 0.f;
        const bool valid = (q < 8) || (tid == 0);
        if (valid) {
            int k  = tid + NT * q;
            int k1 = k & (N2 - 1);
            int k2 = (N2 - k1) & (N2 - 1);
            int pa = __brev((unsigned)k1) >> 21;   // 11-bit reversal
            int pb = __brev((unsigned)k2) >> 21;
            double ar = zre[PD(pa)], ai = zim[PD(pa)];
            double br = zre[PD(pb)], bi = zim[PD(pb)];
            double Er = 0.5 * (ar + br), Ei = 0.5 * (ai - bi);
            double Or = 0.5 * (ai + bi), Oi = 0.5 * (br - ar);
            double cc, ss;
            if (USE_WS) { double2 uv = Ut[k]; cc = uv.x; ss = uv.y; }
            else        { sincospi(-(double)k / 2048.0, &ss, &cc); }
            double Xr = Er + cc * Or - ss * Oi;
            double Xi = Ei + cc * Oi + ss * Or;
            fxr[q] = (float)Xr; fxi[q] = (float)Xi;
            float a2 = (float)(Xr * Xr + Xi * Xi);
            ku[q] = __float_as_uint(a2);
        }
    }

    // ---- exact rank-64 threshold: bitwise descent, 1 barrier per bit
    unsigned prefix = 0;
    int buf = 0;
    for (int bit = 30; bit >= 0; --bit) {
        unsigned cand = prefix | (1u << bit);
        int cnt = 0;
        #pragma unroll
        for (int q = 0; q < 9; ++q) cnt += (ku[q] >= cand) ? 1 : 0;  // invalid ku==0 < cand
        for (int off = 1; off < 64; off <<= 1) cnt += __shfl_xor(cnt, off);
        if (lane == 0) red[buf][w] = cnt;
        __syncthreads();
        int tot = red[buf][0] + red[buf][1] + red[buf][2] + red[buf][3];
        if (tot >= KTOP) prefix = cand;
        buf ^= 1;
    }

    // counts at threshold (packed ge | gt<<16)
    int cge = 0, cgt = 0;
    #pragma unroll
    for (int q = 0; q < 9; ++q) {
        const bool valid = (q < 8) || (tid == 0);
        if (valid) {
            cge += (ku[q] >= prefix) ? 1 : 0;
            cgt += (ku[q] >  prefix) ? 1 : 0;
        }
    }
    int packed = cge | (cgt << 16);
    for (int off = 1; off < 64; off <<= 1) packed += __shfl_xor(packed, off);
    if (lane == 0) red[buf][w] = packed;
    __syncthreads();
    int tot = red[buf][0] + red[buf][1] + red[buf][2] + red[buf][3];
    cge = tot & 0xFFFF; cgt = tot >> 16;

    // ---- keep decisions (ties: lowest global bin index wins)
    bool kp[9];
    if (cge == KTOP) {
        #pragma unroll
        for (int q = 0; q < 9; ++q) {
            const bool valid = (q < 8) || (tid == 0);
            kp[q] = valid && (ku[q] >= prefix);
        }
    } else {
        int need_eq = KTOP - cgt;
        int mb[9]; bool eqf[9];
        #pragma unroll
        for (int q = 0; q < 9; ++q) {
            const bool valid = (q < 8) || (tid == 0);
            bool eq = valid && (ku[q] == prefix);
            eqf[q] = eq;
            unsigned long long bal = __ballot(eq);
            if (lane == 0) eqc[q][w] = __popcll(bal);
            mb[q] = __popcll(bal & ((1ull << lane) - 1ull));
        }
        __syncthreads();
        int base = 0;
        #pragma unroll
        for (int q = 0; q < 9; ++q) {
            const bool valid = (q < 8) || (tid == 0);
            int pw = 0;
            #pragma unroll
            for (int ww = 0; ww < 4; ++ww) pw += (ww < w) ? eqc[q][ww] : 0;
            int rank = base + pw + mb[q];
            kp[q] = (valid && ku[q] > prefix) || (eqf[q] && rank < need_eq);
            base += eqc[q][0] + eqc[q][1] + eqc[q][2] + eqc[q][3];
        }
    }

    // ---- build compact kept-bin list (order irrelevant for the sum)
    #pragma unroll
    for (int q = 0; q < 9; ++q) {
        if (kp[q]) {
            int k = tid + NT * q;
            int slot = atomicAdd(&nlist, 1);
            float wgt = (k == 0 || k == N2) ? 1.f : 2.f;
            float sd, cd; sincospif((float)(k & 15) * 0.125f, &sd, &cd);  // e^{2pi i k/16}
            listf[slot] = make_float4(wgt * fxr[q], wgt * fxi[q], cd, sd);
            listk[slot] = k;
        }
    }
    __syncthreads();

    // ---- direct sparse inverse: out[t] = (1/N) sum_i (a_i cos - b_i sin),
    // Chebyshev 3-term recurrence over the 16 outputs per thread.
    int n = nlist;
    float acc[16];
    #pragma unroll
    for (int j = 0; j < 16; ++j) acc[j] = 0.f;
    for (int i = 0; i < n; ++i) {
        float4 e = listf[i];     // broadcast reads
        int k = listk[i];
        int m = (k * tid) & (NF - 1);
        float s0, c0; sincospif((float)m * (1.0f / 2048.0f), &s0, &c0);
        float cd = e.z, sd = e.w;
        float g0 = e.x * c0 - e.y * s0;
        float c1 = c0 * cd - s0 * sd;
        float s1 = s0 * cd + c0 * sd;
        float g1 = e.x * c1 - e.y * s1;
        float twoC = cd + cd;
        acc[0] += g0; acc[1] += g1;
        float gp = g0, gc = g1;
        #pragma unroll
        for (int j = 2; j < 16; ++j) {
            float gn = twoC * gc - gp;
            acc[j] += gn;
            gp = gc; gc = gn;
        }
    }

    float* op = out + (size_t)b * LL * CC + c;
    const float invN = 1.0f / (float)NF;
    #pragma unroll
    for (int j = 0; j < 16; ++j)
        op[(size_t)(tid + NT * j) * CC] = acc[j] * invN;
}

extern "C" void kernel_launch(void* const* d_in, const int* in_sizes, int n_in,
                              void* d_out, int out_size, void* d_ws, size_t ws_size,
                              hipStream_t stream) {
    (void)in_sizes; (void)n_in; (void)out_size;
    const float* x = (const float*)d_in[0];
    float* out = (float*)d_out;

    const size_t wbytes = 1024 * sizeof(double2);
    const size_t ubytes = 2049 * sizeof(double2);
    bool use_ws = (ws_size >= wbytes + ubytes);

    dim3 grid(BB * CC), block(NT);
    if (use_ws) {
        double2* Wt = (double2*)d_ws;
        double2* Ut = (double2*)((char*)d_ws + wbytes);
        hipLaunchKernelGGL(init_tables_kernel, dim3(9), dim3(256), 0, stream, Wt, Ut);
        hipLaunchKernelGGL(fourier_topk_kernel<true>, grid, block, 0, stream, x, out, Wt, Ut);
    } else {
        hipLaunchKernelGGL(fourier_topk_kernel<false>, grid, block, 0, stream,
                           x, out, (const double2*)nullptr, (const double2*)nullptr);
    }
}

// Round 3
// 300.722 us; speedup vs baseline: 2.2557x; 1.2583x over previous
//
#include <hip/hip_runtime.h>
#include <math.h>

#define NT   256
#define N2   2048
#define NF   4096
#define KTOP 64
#define BB   32
#define LL   4096
#define CC   128
#define PD(i)  ((i) + ((i) >> 5))   // data padding
#define PDT(i) ((i) + ((i) >> 3))   // twiddle-table padding

union USh {
    double2 zc[2112];           // fwd fp64 interleaved (2048 + pad)
    float   keys[2304];         // topk keys (2049 used)
    float2  zci[2112];          // inverse fp32 interleaved (2048 + pad)
};

__global__ __launch_bounds__(NT, 4)
void fourier_topk_kernel(const float* __restrict__ x, float* __restrict__ out) {
    __shared__ USh u;
    __shared__ double2 Tf[144];   // e^{-i pi k/1024}, k<128 (PDT-indexed)
    __shared__ double2 Ff[8];     // e^{-i pi h/8}
    __shared__ double2 E1s;       // e^{-i pi/2048}
    __shared__ float2  T32[288];  // e^{+i pi k/1024}, k<256 (PDT-indexed)
    __shared__ float2  G4[4];     // e^{+i pi g/4}
    __shared__ unsigned bc_prefix;
    __shared__ int bc_pack;
    __shared__ int eqc[9][4];

    const int tid  = threadIdx.x;
    const int lane = tid & 63;
    const int w    = tid >> 6;

    // XCD-aware swizzle: 16 consecutive channels stay on one XCD
    int d = blockIdx.x;
    int xcd = d & 7, slot = d >> 3;
    int cid = xcd * 32 + (slot >> 4);
    int within = slot & 15;
    int b = cid >> 3;
    int c = ((cid & 7) << 4) + within;

    const float* xp = x + (size_t)b * LL * CC + c;

    // ---- build tables (once per block, parallel)
    if (tid < 128) { double s, cc; sincospi(-(double)tid / 1024.0, &s, &cc); Tf[PDT(tid)] = make_double2(cc, s); }
    if (tid < 8)   { double s, cc; sincospi(-(double)tid / 8.0,    &s, &cc); Ff[tid]      = make_double2(cc, s); }
    if (tid == 8)  { double s, cc; sincospi(-1.0 / 2048.0,         &s, &cc); E1s          = make_double2(cc, s); }
    { float s, cc; sincospif((float)tid / 1024.0f, &s, &cc); T32[PDT(tid)] = make_float2(cc, s); }
    if (tid < 4)   { float s, cc; sincospif((float)tid / 4.0f, &s, &cc); G4[tid] = make_float2(cc, s); }

    // ---- load real series packed: z[m] = x[2m] + i*x[2m+1]
    #pragma unroll
    for (int i = 0; i < 8; ++i) {
        int m = tid + NT * i;
        float ev = xp[(size_t)(2 * m)     * CC];
        float od = xp[(size_t)(2 * m + 1) * CC];
        u.zc[PD(m)] = make_double2((double)ev, (double)od);
    }
    __syncthreads();

    // ---- forward fp64 radix-2^2 DIF: 5 double-stages + final radix-2
    #pragma unroll
    for (int LH = 10; LH >= 2; LH -= 2) {
        const int h = 1 << LH, q = h >> 1;
        #pragma unroll
        for (int it = 0; it < 2; ++it) {
            int bf  = tid + NT * it;            // 0..511
            int j   = bf & (q - 1);
            int blk = bf >> (LH - 1);
            int a   = (blk << (LH + 1)) + j;
            double2 x0 = u.zc[PD(a)],     x1 = u.zc[PD(a + q)];
            double2 x2 = u.zc[PD(a + h)], x3 = u.zc[PD(a + h + q)];
            int e1 = j << (10 - LH);            // j*1024/h < 512
            double2 t = Tf[PDT(e1 & 127)];
            double2 f = Ff[e1 >> 7];
            double wc  = t.x * f.x - t.y * f.y, ws  = t.x * f.y + t.y * f.x;  // W1
            double w2c = wc * wc - ws * ws,     w2s = 2.0 * wc * ws;          // W1^2
            // stage A (half=h): pairs (x0,x2) twiddle W1; (x1,x3) twiddle W1*(-i)
            double u0r = x0.x + x2.x, u0i = x0.y + x2.y;
            double d0r = x0.x - x2.x, d0i = x0.y - x2.y;
            double u1r = x1.x + x3.x, u1i = x1.y + x3.y;
            double d1r = x1.x - x3.x, d1i = x1.y - x3.y;
            double v0r = d0r * wc - d0i * ws,  v0i = d0r * ws + d0i * wc;
            double v1r = d1r * ws + d1i * wc,  v1i = d1i * ws - d1r * wc;     // *(ws,-wc)
            // stage B (half=q): (u0,u1) and (v0,v1), twiddle W2
            double s0r = u0r + u1r, s0i = u0i + u1i;
            double e0r = u0r - u1r, e0i = u0i - u1i;
            double s1r = v0r + v1r, s1i = v0i + v1i;
            double e1r = v0r - v1r, e1i = v0i - v1i;
            u.zc[PD(a)]         = make_double2(s0r, s0i);
            u.zc[PD(a + q)]     = make_double2(e0r * w2c - e0i * w2s, e0r * w2s + e0i * w2c);
            u.zc[PD(a + h)]     = make_double2(s1r, s1i);
            u.zc[PD(a + h + q)] = make_double2(e1r * w2c - e1i * w2s, e1r * w2s + e1i * w2c);
        }
        __syncthreads();
    }
    #pragma unroll
    for (int it = 0; it < 4; ++it) {            // final radix-2, half=1, W=1
        int a = 2 * (tid + NT * it);
        double2 x0 = u.zc[PD(a)], x1 = u.zc[PD(a + 1)];
        u.zc[PD(a)]     = make_double2(x0.x + x1.x, x0.y + x1.y);
        u.zc[PD(a + 1)] = make_double2(x0.x - x1.x, x0.y - x1.y);
    }
    __syncthreads();

    // ---- untwiddle to rfft bins (registers)
    unsigned ku[9]; float fxr[9], fxi[9];
    #pragma unroll
    for (int q9 = 0; q9 < 9; ++q9) {
        int k = tid + NT * q9;
        const bool valid = (q9 < 8) || (tid == 0);
        ku[q9] = 0u; fxr[q9] = 0.f; fxi[q9] = 0.f;
        if (valid) {
            int k1 = k & (N2 - 1), k2 = (N2 - k1) & (N2 - 1);
            int pa = __brev((unsigned)k1) >> 21, pb = __brev((unsigned)k2) >> 21;
            double2 A = u.zc[PD(pa)], Bz = u.zc[PD(pb)];
            double Er = 0.5 * (A.x + Bz.x), Ei = 0.5 * (A.y - Bz.y);
            double Or = 0.5 * (A.y + Bz.y), Oi = 0.5 * (Bz.x - A.x);
            double Xr, Xi;
            if (k == N2) { Xr = Er - Or; Xi = 0.0; }
            else {
                int m = k >> 1, r = k & 1;
                double2 t = Tf[PDT(m & 127)], f = Ff[m >> 7];
                double uc = t.x * f.x - t.y * f.y, us = t.x * f.y + t.y * f.x;
                if (r) {
                    double nc = uc * E1s.x - us * E1s.y;
                    us = uc * E1s.y + us * E1s.x; uc = nc;
                }
                Xr = Er + uc * Or - us * Oi;
                Xi = Ei + uc * Oi + us * Or;
            }
            fxr[q9] = (float)Xr; fxi[q9] = (float)Xi;
            float a2 = (float)(Xr * Xr + Xi * Xi);
            ku[q9] = __float_as_uint(a2);
        }
    }
    __syncthreads();                       // zc reads done

    // ---- stage keys into (dead) LDS; single-wave rank-64 bit descent
    #pragma unroll
    for (int q9 = 0; q9 < 9; ++q9) u.keys[tid + NT * q9] = __uint_as_float(ku[q9]);
    __syncthreads();

    if (tid < 64) {
        unsigned lk[36];
        #pragma unroll
        for (int i = 0; i < 36; ++i) lk[i] = __float_as_uint(u.keys[tid + 64 * i]);
        unsigned prefix = 0;
        for (int bit = 30; bit >= 0; --bit) {
            unsigned cand = prefix | (1u << bit);
            int cnt = 0;
            #pragma unroll
            for (int i = 0; i < 36; ++i) cnt += (lk[i] >= cand) ? 1 : 0;
            for (int off = 1; off < 64; off <<= 1) cnt += __shfl_xor(cnt, off);
            if (cnt >= KTOP) prefix = cand;
        }
        int cge = 0, cgt = 0;
        #pragma unroll
        for (int i = 0; i < 36; ++i) { cge += (lk[i] >= prefix) ? 1 : 0; cgt += (lk[i] > prefix) ? 1 : 0; }
        int packed = cge | (cgt << 16);
        for (int off = 1; off < 64; off <<= 1) packed += __shfl_xor(packed, off);
        if (tid == 0) { bc_prefix = prefix; bc_pack = packed; }
    }
    __syncthreads();
    const unsigned prefix = bc_prefix;
    const int cge = bc_pack & 0xFFFF, cgt = bc_pack >> 16;

    // ---- keep decisions (ties: lowest bin index wins)
    bool kp[9];
    if (cge == KTOP) {
        #pragma unroll
        for (int q9 = 0; q9 < 9; ++q9) {
            const bool valid = (q9 < 8) || (tid == 0);
            kp[q9] = valid && (ku[q9] >= prefix);
        }
    } else {
        int need_eq = KTOP - cgt;
        int mb[9]; bool eqf[9];
        #pragma unroll
        for (int q9 = 0; q9 < 9; ++q9) {
            const bool valid = (q9 < 8) || (tid == 0);
            bool eq = valid && (ku[q9] == prefix);
            eqf[q9] = eq;
            unsigned long long bal = __ballot(eq);
            if (lane == 0) eqc[q9][w] = __popcll(bal);
            mb[q9] = __popcll(bal & ((1ull << lane) - 1ull));
        }
        __syncthreads();
        int base = 0;
        #pragma unroll
        for (int q9 = 0; q9 < 9; ++q9) {
            const bool valid = (q9 < 8) || (tid == 0);
            int pw = 0;
            #pragma unroll
            for (int ww = 0; ww < 4; ++ww) pw += (ww < w) ? eqc[q9][ww] : 0;
            int rank = base + pw + mb[q9];
            kp[q9] = (valid && ku[q9] > prefix) || (eqf[q9] && rank < need_eq);
            base += eqc[q9][0] + eqc[q9][1] + eqc[q9][2] + eqc[q9][3];
        }
    }
    __syncthreads();                       // keys dead; zci region reusable

    // ---- zero sparse spectrum
    #pragma unroll
    for (int i = 0; i < 9; ++i) {
        int idx = tid + NT * i;
        if (idx < 2112) u.zci[idx] = make_float2(0.f, 0.f);
    }
    __syncthreads();

    // ---- scatter kept bins into packed half-spectrum, bit-reversed positions
    // Z[k] += X*P,  Z[2048-k] += conj(X)*Q,  P=(1+i e^{i pi k/2048})/2, Q=1-conj(P)
    float* zf = (float*)u.zci;
    #pragma unroll
    for (int q9 = 0; q9 < 9; ++q9) {
        if (kp[q9]) {
            int k = tid + NT * q9;
            float a = fxr[q9], bq = fxi[q9];
            float sth, cth; sincospif((float)k * (1.0f / 2048.0f), &sth, &cth);
            float Px = 0.5f * (1.f - sth), Py = 0.5f * cth;
            if (k < N2) {
                int p = PD((int)(__brev((unsigned)k) >> 21));
                atomicAdd(&zf[2 * p],     a * Px - bq * Py);
                atomicAdd(&zf[2 * p + 1], a * Py + bq * Px);
            }
            if (k > 0) {
                int m2 = (N2 - k) & (N2 - 1);
                int p = PD((int)(__brev((unsigned)m2) >> 21));
                float Qx = 1.f - Px, Qy = Py;
                atomicAdd(&zf[2 * p],     a * Qx + bq * Qy);
                atomicAdd(&zf[2 * p + 1], a * Qy - bq * Qx);
            }
        }
    }
    __syncthreads();

    // ---- inverse fp32 radix-2^2 DIT (bit-reversed in -> natural out)
    #pragma unroll
    for (int LH = 0; LH <= 8; LH += 2) {
        const int h = 1 << LH;
        #pragma unroll
        for (int it = 0; it < 2; ++it) {
            int bf  = tid + NT * it;            // 0..511
            int j   = bf & (h - 1);
            int blk = bf >> LH;
            int a   = (blk << (LH + 2)) + j;
            float2 x0 = u.zci[PD(a)],         x1 = u.zci[PD(a + h)];
            float2 x2 = u.zci[PD(a + 2 * h)], x3 = u.zci[PD(a + 3 * h)];
            int eB = j << (9 - LH);             // j*512/h < 512
            float2 t = T32[PDT(eB & 255)];
            float2 g = G4[eB >> 8];
            float wbc = t.x * g.x - t.y * g.y, wbs = t.x * g.y + t.y * g.x;  // WB
            float wac = wbc * wbc - wbs * wbs, was = 2.f * wbc * wbs;        // WA=WB^2
            float vr = x1.x * wac - x1.y * was, vi = x1.x * was + x1.y * wac;
            float y0r = x0.x + vr, y0i = x0.y + vi, y1r = x0.x - vr, y1i = x0.y - vi;
            float ur = x3.x * wac - x3.y * was, ui = x3.x * was + x3.y * wac;
            float y2r = x2.x + ur, y2i = x2.y + ui, y3r = x2.x - ur, y3i = x2.y - ui;
            float b0r = y2r * wbc - y2i * wbs, b0i = y2r * wbs + y2i * wbc;
            float b1r = -(y3r * wbs) - y3i * wbc, b1i = y3r * wbc - y3i * wbs; // *(WB*i)
            u.zci[PD(a)]         = make_float2(y0r + b0r, y0i + b0i);
            u.zci[PD(a + 2 * h)] = make_float2(y0r - b0r, y0i - b0i);
            u.zci[PD(a + h)]     = make_float2(y1r + b1r, y1i + b1i);
            u.zci[PD(a + 3 * h)] = make_float2(y1r - b1r, y1i - b1i);
        }
        __syncthreads();
    }
    #pragma unroll
    for (int it = 0; it < 4; ++it) {            // final DIT stage, half=1024
        int j = tid + NT * it;                  // 0..1023
        float2 x0 = u.zci[PD(j)], x1 = u.zci[PD(j + 1024)];
        float2 t = T32[PDT(j & 255)];
        float2 g = G4[j >> 8];
        float wc = t.x * g.x - t.y * g.y, ws = t.x * g.y + t.y * g.x;  // e^{+i pi j/1024}
        float vr = x1.x * wc - x1.y * ws, vi = x1.x * ws + x1.y * wc;
        u.zci[PD(j)]        = make_float2(x0.x + vr, x0.y + vi);
        u.zci[PD(j + 1024)] = make_float2(x0.x - vr, x0.y - vi);
    }
    __syncthreads();

    // ---- unpack + write: x[2m] = Re z[m]/2048, x[2m+1] = Im z[m]/2048
    float* op = out + (size_t)b * LL * CC + c;
    const float inv = 1.0f / 2048.0f;
    #pragma unroll
    for (int i = 0; i < 8; ++i) {
        int m = tid + NT * i;
        float2 z = u.zci[PD(m)];
        op[(size_t)(2 * m)     * CC] = z.x * inv;
        op[(size_t)(2 * m + 1) * CC] = z.y * inv;
    }
}

extern "C" void kernel_launch(void* const* d_in, const int* in_sizes, int n_in,
                              void* d_out, int out_size, void* d_ws, size_t ws_size,
                              hipStream_t stream) {
    (void)in_sizes; (void)n_in; (void)d_ws; (void)ws_size; (void)out_size;
    const float* x = (const float*)d_in[0];
    float* out = (float*)d_out;
    dim3 grid(BB * CC), block(NT);
    hipLaunchKernelGGL(fourier_topk_kernel, grid, block, 0, stream, x, out);
}